// Round 17
// baseline (77.045 us; speedup 1.0000x reference)
//
#include <hip/hip_runtime.h>
#include <hip/hip_fp16.h>

namespace {

constexpr int B  = 4;
constexpr int V  = 5000;
constexpr int NF = 10000;
constexpr int H  = 512;
constexpr int W  = 512;
constexpr int HW = H * W;          // 2^18
constexpr int NPIX = B * HW;
constexpr int CAP = 32;            // max vertex degree bucket (validated r12-15)
constexpr int BNF = B * NF;
constexpr int BV  = B * V;

// output float offsets
constexpr int OFF_IMAGES  = 0;
constexpr int OFF_ALBEDO  = 3 * NPIX;
constexpr int OFF_ALPHA   = OFF_ALBEDO + 3 * NPIX;
constexpr int OFF_POSMASK = OFF_ALPHA + NPIX;
constexpr int OFF_SHADING = OFF_POSMASK + NPIX;
constexpr int OFF_GRID    = OFF_SHADING + 3 * NPIX;
constexpr int OFF_NORMALS = OFF_GRID + 2 * NPIX;

// SH constants
constexpr float C0 = 0.28209479177387814f;
constexpr float C1 = 1.0233267079464885f;
constexpr float C4 = 0.8580855308097834f;
constexpr float C7 = 0.42904276540489156f;
constexpr float C8 = 0.24770795610037571f;

typedef float f32x4 __attribute__((ext_vector_type(4)));
typedef int   i32x4 __attribute__((ext_vector_type(4)));

__device__ inline float2 unpack_h2(float fbits) {
    __half2 h = *reinterpret_cast<__half2*>(&fbits);
    return __half22float2(h);
}
// albedo 11/11/10 fixed-point pack (values in [0,1)); err <= 4.9e-4
__device__ inline unsigned quant_rgb(float r, float g, float bch) {
    unsigned qr = (unsigned)fmaf(r,   2047.0f, 0.5f);
    unsigned qg = (unsigned)fmaf(g,   2047.0f, 0.5f);
    unsigned qb = (unsigned)fmaf(bch, 1023.0f, 0.5f);
    return qr | (qg << 11) | (qb << 22);
}
__device__ inline float3 dequant_rgb(unsigned w) {
    return make_float3((float)(w & 2047u)         * (1.0f/2047.0f),
                       (float)((w >> 11) & 2047u) * (1.0f/2047.0f),
                       (float)(w >> 22)           * (1.0f/1023.0f));
}
__device__ inline void nt_store4(float* p, float4 v) {
    __builtin_nontemporal_store(*reinterpret_cast<const f32x4*>(&v), (f32x4*)p);
}
__device__ inline float4 nt_load4f(const float* p) {
    f32x4 t = __builtin_nontemporal_load((const f32x4*)p);
    return *reinterpret_cast<float4*>(&t);
}
__device__ inline int4 nt_load4i(const int* p) {
    i32x4 t = __builtin_nontemporal_load((const i32x4*)p);
    return *reinterpret_cast<int4*>(&t);
}

// ---------------------------------------------------------------------------
// ftab row: 16 float lanes (64B, one aligned line):
//  0:u0 1:v0 2:u1 3:v1 4:u2 5:v2 6:tz0 7:tz1 8:tz2
//  9..13: 9 fp16 normals as half-lanes h[18..26] = n0x n0y n0z n1x n1y n1z n2x n2y n2z
// bigfill writes lanes 0-5; vsum scatters lanes 6-8 (fp32) + halves 18-26.
// key = phase*NF + f ; phase 0 = slot1, 1 = slot2, 2 = slot0 (reference order)
// ---------------------------------------------------------------------------
__global__ __launch_bounds__(256) void bigfill_k(
    const int*   __restrict__ faces,
    const float* __restrict__ fuv,
    const float* __restrict__ verts,
    const float* __restrict__ tverts,
    const float* __restrict__ albedo,
    int*         __restrict__ cnt,
    float4*      __restrict__ fng,
    float4*      __restrict__ fnt,
    float*       __restrict__ ftab,
    unsigned*    __restrict__ apack) {
    int gid = blockIdx.x * 256 + threadIdx.x;
    if (gid < V) cnt[gid] = 0;     // cnt consumed only by fill_k (next node)
    if (gid < NPIX) {
        int b = gid >> 18, hw = gid & (HW - 1);
        const float* ab = albedo + (size_t)b * 3 * HW;
        float r  = __builtin_nontemporal_load(ab + hw);
        float g  = __builtin_nontemporal_load(ab + HW + hw);
        float bl = __builtin_nontemporal_load(ab + 2*HW + hw);
        apack[gid] = quant_rgb(r, g, bl);
        return;
    }
    int i = gid - NPIX;
    if (i >= BNF) return;
    int b = i / NF, f = i - b * NF;
    int j0 = faces[f*3+0], j1 = faces[f*3+1], j2 = faces[f*3+2];

    {
        const float* vb = verts + (size_t)b * V * 3;
        float x0 = vb[j0*3], y0 = vb[j0*3+1], z0 = vb[j0*3+2];
        float x1 = vb[j1*3], y1 = vb[j1*3+1], z1 = vb[j1*3+2];
        float x2 = vb[j2*3], y2 = vb[j2*3+1], z2 = vb[j2*3+2];
        {
            float ax=x2-x1, ay=y2-y1, az=z2-z1, bx=x0-x1, by=y0-y1, bz=z0-z1;
            fng[0*BNF + i] = make_float4(ay*bz - az*by, az*bx - ax*bz, ax*by - ay*bx, 0.f);
        }
        {
            float ax=x0-x2, ay=y0-y2, az=z0-z2, bx=x1-x2, by=y1-y2, bz=z1-z2;
            fng[1*BNF + i] = make_float4(ay*bz - az*by, az*bx - ax*bz, ax*by - ay*bx, 0.f);
        }
        {
            float ax=x1-x0, ay=y1-y0, az=z1-z0, bx=x2-x0, by=y2-y0, bz=z2-z0;
            fng[2*BNF + i] = make_float4(ay*bz - az*by, az*bx - ax*bz, ax*by - ay*bx, 0.f);
        }
    }
    {
        const float* tb = tverts + (size_t)b * V * 3;
        // replicate reference rounding: z += 10 BEFORE edges
        float x0 = tb[j0*3], y0 = tb[j0*3+1], z0 = tb[j0*3+2] + 10.0f;
        float x1 = tb[j1*3], y1 = tb[j1*3+1], z1 = tb[j1*3+2] + 10.0f;
        float x2 = tb[j2*3], y2 = tb[j2*3+1], z2 = tb[j2*3+2] + 10.0f;
        {
            float ax=x2-x1, ay=y2-y1, az=z2-z1, bx=x0-x1, by=y0-y1, bz=z0-z1;
            fnt[0*BNF + i] = make_float4(ay*bz - az*by, az*bx - ax*bz, ax*by - ay*bx, 0.f);
        }
        {
            float ax=x0-x2, ay=y0-y2, az=z0-z2, bx=x1-x2, by=y1-y2, bz=z1-z2;
            fnt[1*BNF + i] = make_float4(ay*bz - az*by, az*bx - ax*bz, ax*by - ay*bx, 0.f);
        }
        {
            float ax=x1-x0, ay=y1-y0, az=z1-z0, bx=x2-x0, by=y2-y0, bz=z2-z0;
            fnt[2*BNF + i] = make_float4(ay*bz - az*by, az*bx - ax*bz, ax*by - ay*bx, 0.f);
        }
    }
    // uv lanes 0-5
    const float* uv = fuv + (size_t)f * 9;
    float* row = ftab + (size_t)i * 16;
    *(float4*)(row + 0) = make_float4(uv[0], uv[1], uv[3], uv[4]);
    *(float2*)(row + 4) = make_float2(uv[6], uv[7]);
}

// bucket fill (needs zeroed cnt from bigfill)
__global__ void fill_k(const int* __restrict__ faces, int* __restrict__ cnt,
                       int* __restrict__ keys) {
    int f = blockIdx.x * blockDim.x + threadIdx.x;
    if (f >= NF) return;
    int j0 = faces[f*3+0], j1 = faces[f*3+1], j2 = faces[f*3+2];
    int p;
    p = atomicAdd(&cnt[j1], 1); if (p < CAP) keys[j1*CAP + p] = 0*NF + f;
    p = atomicAdd(&cnt[j2], 1); if (p < CAP) keys[j2*CAP + p] = 1*NF + f;
    p = atomicAdd(&cnt[j0], 1); if (p < CAP) keys[j0*CAP + p] = 2*NF + f;
}

// ---------------------------------------------------------------------------
// vsum: 2*B*V threads; keys in registers; unrolled min-scan selection gives
// exact reference (phase-major, face-ascending) accumulation order. Then
// scatter results straight into ftab (geo: 2B half stores; transformed: 4B).
// ---------------------------------------------------------------------------
__global__ __launch_bounds__(256) void vsum_k(
    const int*    __restrict__ cnt,
    const int*    __restrict__ keys,
    const float4* __restrict__ fng,
    const float4* __restrict__ fnt,
    float*        __restrict__ normV,
    float*        __restrict__ ftab) {
    int id = blockIdx.x * 256 + threadIdx.x;
    if (id >= 2 * BV) return;
    int half = (id >= BV) ? 1 : 0;
    int i = id - half * BV;
    int b = i / V, v = i - b * V;

    int n = min(cnt[v], CAP);
    int ks[CAP];
    const int4* kp = (const int4*)(keys + (size_t)v * CAP);
#pragma unroll
    for (int j = 0; j < CAP/4; ++j) {
        int4 t = kp[j];
        ks[4*j+0] = t.x; ks[4*j+1] = t.y; ks[4*j+2] = t.z; ks[4*j+3] = t.w;
    }
#pragma unroll
    for (int j = 0; j < CAP; ++j) ks[j] = (j < n) ? ks[j] : 0x7fffffff;

    const float4* src = half ? fnt : fng;
    float sx = 0.f, sy = 0.f, sz = 0.f;
    int last = -1;
    for (int e = 0; e < n; ++e) {
        int cur = 0x7fffffff;
#pragma unroll
        for (int j = 0; j < CAP; ++j) {
            int k = ks[j];
            bool g = (k > last) && (k < cur);
            cur = g ? k : cur;
        }
        last = cur;
        int phase = (cur >= 2*NF) ? 2 : (cur >= NF ? 1 : 0);
        int f = cur - phase * NF;
        float4 t = src[phase * BNF + b * NF + f];
        sx += t.x; sy += t.y; sz += t.z;
    }
    float inv = 1.0f / fmaxf(sqrtf(sx*sx + sy*sy + sz*sz), 1e-6f);
    if (half == 0) {
        sx *= inv; sy *= inv; sz *= inv;
        normV[i*3+0] = sx; normV[i*3+1] = sy; normV[i*3+2] = sz;
        __half hx = __float2half(sx), hy = __float2half(sy), hz = __float2half(sz);
#pragma unroll
        for (int j = 0; j < CAP; ++j) {
            if (j < n) {
                int k = ks[j];
                int phase = (k >= 2*NF) ? 2 : (k >= NF ? 1 : 0);
                int f = k - phase * NF;
                int corner = (phase == 0) ? 1 : (phase == 1 ? 2 : 0);
                __half* hp = (__half*)(ftab + ((size_t)b*NF + f) * 16);
                hp[18 + 3*corner + 0] = hx;
                hp[18 + 3*corner + 1] = hy;
                hp[18 + 3*corner + 2] = hz;
            }
        }
    } else {
        float tnz = sz * inv;
#pragma unroll
        for (int j = 0; j < CAP; ++j) {
            if (j < n) {
                int k = ks[j];
                int phase = (k >= 2*NF) ? 2 : (k >= NF ? 1 : 0);
                int f = k - phase * NF;
                int corner = (phase == 0) ? 1 : (phase == 1 ? 2 : 0);
                ftab[((size_t)b*NF + f) * 16 + 6 + corner] = tnz;
            }
        }
    }
}

// ---------------------------------------------------------------------------
// pixel: 4 adjacent pixels per thread, XCD-swizzled blocks; NT streaming IO.
// ---------------------------------------------------------------------------
struct PixR { float u, v, s0, s1, s2, a0, a1, a2, vis, tz; };

__device__ inline PixR shade_px(int f, float b0, float b1, float b2, int b,
                                const float* __restrict__ ftab,
                                const unsigned* __restrict__ apack,
                                const float* __restrict__ L) {
    PixR r;
    r.vis = (f >= 0) ? 1.0f : 0.0f;
    int fs = (f >= 0) ? f : 0;
    float w0 = b0 * r.vis, w1 = b1 * r.vis, w2 = b2 * r.vis;
    const float4* fr = (const float4*)(ftab + (size_t)fs * 16);
    float4 qa = fr[0];                         // u0,v0,u1,v1
    float4 qb = fr[1];                         // u2,v2,tz0,tz1
    float4 qc = fr[2];                         // tz2, p0, p1, p2
    float2 qd = *(const float2*)(ftab + (size_t)fs * 16 + 12); // p3, p4
    r.u  = w0*qa.x + w1*qa.z + w2*qb.x;
    r.v  = w0*qa.y + w1*qa.w + w2*qb.y;
    r.tz = w0*qb.z + w1*qb.w + w2*qc.x;
    float2 p0 = unpack_h2(qc.y);   // n0x,n0y
    float2 p1 = unpack_h2(qc.z);   // n0z,n1x
    float2 p2 = unpack_h2(qc.w);   // n1y,n1z
    float2 p3 = unpack_h2(qd.x);   // n2x,n2y
    float2 p4 = unpack_h2(qd.y);   // n2z,-
    float nx = w0*p0.x + w1*p1.y + w2*p3.x;
    float ny = w0*p0.y + w1*p2.x + w2*p3.y;
    float nz = w0*p1.x + w1*p2.y + w2*p4.x;

    float shb[9] = {C0, C1*nx, C1*ny, C1*nz, C4*nx*ny, C4*nx*nz, C4*ny*nz,
                    C7*(nx*nx - ny*ny), C8*(3.0f*nz*nz - 1.0f)};
    float s0 = 0.0f, s1 = 0.0f, s2 = 0.0f;
#pragma unroll
    for (int k = 0; k < 9; ++k) {
        float sk = shb[k];
        s0 += L[k*3+0]*sk; s1 += L[k*3+1]*sk; s2 += L[k*3+2]*sk;
    }
    r.s0 = s0; r.s1 = s1; r.s2 = s2;

    float gx = (r.u + 1.0f) * 0.5f * (float)W - 0.5f;
    float gy = (r.v + 1.0f) * 0.5f * (float)H - 0.5f;
    float x0 = floorf(gx), y0 = floorf(gy);
    float wx1 = gx - x0, wx0 = 1.0f - wx1;
    float wy1 = gy - y0, wy0 = 1.0f - wy1;
    float a0 = 0.0f, a1 = 0.0f, a2 = 0.0f;
    float fx[4] = {x0, x0 + 1.0f, x0,        x0 + 1.0f};
    float fy[4] = {y0, y0,        y0 + 1.0f, y0 + 1.0f};
    float wt[4] = {wx0*wy0, wx1*wy0, wx0*wy1, wx1*wy1};
#pragma unroll
    for (int c = 0; c < 4; ++c) {
        bool valid = (fx[c] >= 0.0f) && (fx[c] <= (float)(W-1)) &&
                     (fy[c] >= 0.0f) && (fy[c] <= (float)(H-1));
        if (valid) {
            int ix = (int)fx[c];
            int iy = (int)fy[c];
            float3 t = dequant_rgb(apack[(b << 18) + iy * W + ix]);
            float wgt = wt[c];
            a0 += wgt * t.x; a1 += wgt * t.y; a2 += wgt * t.z;
        }
    }
    r.a0 = a0; r.a1 = a1; r.a2 = a2;
    return r;
}

__global__ __launch_bounds__(256) void pixel_k(
    const int*    __restrict__ ptf,
    const float*  __restrict__ bary,
    const unsigned* __restrict__ apack,
    const float*  __restrict__ lights,
    const float*  __restrict__ ftab,
    float*        __restrict__ out) {
    // 1024 blocks; XCD swizzle -> contiguous 128-block chunk per XCD
    int bid = blockIdx.x;
    int dataBid = (bid & 7) * (NPIX / 1024 / 8) + (bid >> 3);
    int pix = dataBid * 1024 + threadIdx.x * 4;    // 4 adjacent px, same batch
    int b  = pix >> 18;
    int hw = pix & (HW - 1);

    int4 ff = nt_load4i(ptf + pix);
    const float* bb = bary + (size_t)pix * 3;
    float4 c0 = nt_load4f(bb + 0);
    float4 c1 = nt_load4f(bb + 4);
    float4 c2 = nt_load4f(bb + 8);
    const float* L = lights + (size_t)__builtin_amdgcn_readfirstlane(b) * 27;

    PixR P0 = shade_px(ff.x, c0.x, c0.y, c0.z, b, ftab, apack, L);
    PixR P1 = shade_px(ff.y, c0.w, c1.x, c1.y, b, ftab, apack, L);
    PixR P2 = shade_px(ff.z, c1.z, c1.w, c2.x, b, ftab, apack, L);
    PixR P3 = shade_px(ff.w, c2.y, c2.z, c2.w, b, ftab, apack, L);

    int obase = b * 3 * HW + hw;
    nt_store4(out + OFF_IMAGES + obase        , make_float4(
        P0.a0*P0.s0*P0.vis, P1.a0*P1.s0*P1.vis, P2.a0*P2.s0*P2.vis, P3.a0*P3.s0*P3.vis));
    nt_store4(out + OFF_IMAGES + obase +  HW  , make_float4(
        P0.a1*P0.s1*P0.vis, P1.a1*P1.s1*P1.vis, P2.a1*P2.s1*P2.vis, P3.a1*P3.s1*P3.vis));
    nt_store4(out + OFF_IMAGES + obase + 2*HW , make_float4(
        P0.a2*P0.s2*P0.vis, P1.a2*P1.s2*P1.vis, P2.a2*P2.s2*P2.vis, P3.a2*P3.s2*P3.vis));
    nt_store4(out + OFF_ALBEDO + obase        , make_float4(P0.a0, P1.a0, P2.a0, P3.a0));
    nt_store4(out + OFF_ALBEDO + obase +  HW  , make_float4(P0.a1, P1.a1, P2.a1, P3.a1));
    nt_store4(out + OFF_ALBEDO + obase + 2*HW , make_float4(P0.a2, P1.a2, P2.a2, P3.a2));
    nt_store4(out + OFF_ALPHA   + pix, make_float4(P0.vis, P1.vis, P2.vis, P3.vis));
    nt_store4(out + OFF_POSMASK + pix, make_float4(
        P0.tz < -0.05f ? 1.0f : 0.0f, P1.tz < -0.05f ? 1.0f : 0.0f,
        P2.tz < -0.05f ? 1.0f : 0.0f, P3.tz < -0.05f ? 1.0f : 0.0f));
    nt_store4(out + OFF_SHADING + obase       , make_float4(P0.s0, P1.s0, P2.s0, P3.s0));
    nt_store4(out + OFF_SHADING + obase +  HW , make_float4(P0.s1, P1.s1, P2.s1, P3.s1));
    nt_store4(out + OFF_SHADING + obase + 2*HW, make_float4(P0.s2, P1.s2, P2.s2, P3.s2));
    nt_store4(out + OFF_GRID + (size_t)pix*2    , make_float4(P0.u, P0.v, P1.u, P1.v));
    nt_store4(out + OFF_GRID + (size_t)pix*2 + 4, make_float4(P2.u, P2.v, P3.u, P3.v));
}

} // namespace

extern "C" void kernel_launch(void* const* d_in, const int* in_sizes, int n_in,
                              void* d_out, int out_size, void* d_ws, size_t ws_size,
                              hipStream_t stream) {
    const float* verts  = (const float*)d_in[0];
    const float* tverts = (const float*)d_in[1];
    const float* albedo = (const float*)d_in[2];
    const float* lights = (const float*)d_in[3];
    const float* fuv    = (const float*)d_in[4];
    const float* bary   = (const float*)d_in[5];
    const int*   faces  = (const int*)d_in[6];
    const int*   ptf    = (const int*)d_in[7];
    float* out = (float*)d_out;

    char* ws = (char*)d_ws;
    int*    cnt   = (int*)ws;                               // V
    int*    keys  = cnt + V;                                // V*CAP
    char*   pend  = (char*)(keys + (size_t)V*CAP);
    size_t base      = (size_t)(pend - ws);
    size_t fng_off   = (base + 255) & ~(size_t)255;
    size_t fnt_off   = (fng_off + (size_t)3*BNF*sizeof(float4) + 255) & ~(size_t)255;
    size_t ftab_off  = (fnt_off + (size_t)3*BNF*sizeof(float4) + 255) & ~(size_t)255;
    size_t apack_off = (ftab_off + (size_t)BNF*16*sizeof(float) + 255) & ~(size_t)255;
    float4*   fng   = (float4*)(ws + fng_off);              // 1.92 MB
    float4*   fnt   = (float4*)(ws + fnt_off);              // 1.92 MB
    float*    ftab  = (float*)(ws + ftab_off);              // 2.56 MB (64B rows)
    unsigned* apack = (unsigned*)(ws + apack_off);          // 4.19 MB
    float* normV = out + OFF_NORMALS;

    bigfill_k<<<(NPIX + BNF + 255)/256, 256, 0, stream>>>(faces, fuv, verts, tverts,
                                                          albedo, cnt, fng, fnt,
                                                          ftab, apack);
    fill_k<<<(NF + 255)/256, 256, 0, stream>>>(faces, cnt, keys);
    vsum_k<<<(2*BV + 255)/256, 256, 0, stream>>>(cnt, keys, fng, fnt, normV, ftab);
    pixel_k<<<NPIX/1024, 256, 0, stream>>>(ptf, bary, apack, lights, ftab, out);
}

// Round 18
// 75.330 us; speedup vs baseline: 1.0228x; 1.0228x over previous
//
#include <hip/hip_runtime.h>
#include <hip/hip_fp16.h>

namespace {

constexpr int B  = 4;
constexpr int V  = 5000;
constexpr int NF = 10000;
constexpr int H  = 512;
constexpr int W  = 512;
constexpr int HW = H * W;          // 2^18
constexpr int NPIX = B * HW;
constexpr int CAP = 32;            // max vertex degree bucket (validated r12-17)
constexpr int BNF = B * NF;
constexpr int BV  = B * V;

// output float offsets
constexpr int OFF_IMAGES  = 0;
constexpr int OFF_ALBEDO  = 3 * NPIX;
constexpr int OFF_ALPHA   = OFF_ALBEDO + 3 * NPIX;
constexpr int OFF_POSMASK = OFF_ALPHA + NPIX;
constexpr int OFF_SHADING = OFF_POSMASK + NPIX;
constexpr int OFF_GRID    = OFF_SHADING + 3 * NPIX;
constexpr int OFF_NORMALS = OFF_GRID + 2 * NPIX;

// SH constants
constexpr float C0 = 0.28209479177387814f;
constexpr float C1 = 1.0233267079464885f;
constexpr float C4 = 0.8580855308097834f;
constexpr float C7 = 0.42904276540489156f;
constexpr float C8 = 0.24770795610037571f;

typedef float f32x4 __attribute__((ext_vector_type(4)));

__device__ inline float2 unpack_h2(float fbits) {
    __half2 h = *reinterpret_cast<__half2*>(&fbits);
    return __half22float2(h);
}
// albedo 11/11/10 fixed-point pack (values in [0,1)); err <= 4.9e-4
__device__ inline unsigned quant_rgb(float r, float g, float bch) {
    unsigned qr = (unsigned)fmaf(r,   2047.0f, 0.5f);
    unsigned qg = (unsigned)fmaf(g,   2047.0f, 0.5f);
    unsigned qb = (unsigned)fmaf(bch, 1023.0f, 0.5f);
    return qr | (qg << 11) | (qb << 22);
}
__device__ inline float3 dequant_rgb(unsigned w) {
    return make_float3((float)(w & 2047u)         * (1.0f/2047.0f),
                       (float)((w >> 11) & 2047u) * (1.0f/2047.0f),
                       (float)(w >> 22)           * (1.0f/1023.0f));
}
// NT is used for STORES only (streaming outputs must not evict the L2-resident
// ftab/apack gather set). NT loads were a measured regression (r17: they break
// cache-line sharing between adjacent lanes on coalesced streams).
__device__ inline void nt_store4(float* p, float4 v) {
    __builtin_nontemporal_store(*reinterpret_cast<const f32x4*>(&v), (f32x4*)p);
}

// ---------------------------------------------------------------------------
// ftab row: 16 float lanes (64B, one aligned line):
//  0:u0 1:v0 2:u1 3:v1 4:u2 5:v2 6:tz0 7:tz1 8:tz2
//  9..13: 9 fp16 normals as half-lanes h[18..26] = n0x n0y n0z n1x n1y n1z n2x n2y n2z
// bigfill writes lanes 0-5; vsum scatters lanes 6-8 (fp32) + halves 18-26.
// key = phase*NF + f ; phase 0 = slot1, 1 = slot2, 2 = slot0 (reference order)
// ---------------------------------------------------------------------------
__global__ __launch_bounds__(256) void bigfill_k(
    const int*   __restrict__ faces,
    const float* __restrict__ fuv,
    const float* __restrict__ verts,
    const float* __restrict__ tverts,
    const float* __restrict__ albedo,
    int*         __restrict__ cnt,
    float4*      __restrict__ fng,
    float4*      __restrict__ fnt,
    float*       __restrict__ ftab,
    unsigned*    __restrict__ apack) {
    int gid = blockIdx.x * 256 + threadIdx.x;
    if (gid < V) cnt[gid] = 0;     // cnt consumed only by fill_k (next node)
    if (gid < NPIX) {
        int b = gid >> 18, hw = gid & (HW - 1);
        const float* ab = albedo + (size_t)b * 3 * HW;
        apack[gid] = quant_rgb(ab[hw], ab[HW + hw], ab[2*HW + hw]);
        return;
    }
    int i = gid - NPIX;
    if (i >= BNF) return;
    int b = i / NF, f = i - b * NF;
    int j0 = faces[f*3+0], j1 = faces[f*3+1], j2 = faces[f*3+2];

    {
        const float* vb = verts + (size_t)b * V * 3;
        float x0 = vb[j0*3], y0 = vb[j0*3+1], z0 = vb[j0*3+2];
        float x1 = vb[j1*3], y1 = vb[j1*3+1], z1 = vb[j1*3+2];
        float x2 = vb[j2*3], y2 = vb[j2*3+1], z2 = vb[j2*3+2];
        {
            float ax=x2-x1, ay=y2-y1, az=z2-z1, bx=x0-x1, by=y0-y1, bz=z0-z1;
            fng[0*BNF + i] = make_float4(ay*bz - az*by, az*bx - ax*bz, ax*by - ay*bx, 0.f);
        }
        {
            float ax=x0-x2, ay=y0-y2, az=z0-z2, bx=x1-x2, by=y1-y2, bz=z1-z2;
            fng[1*BNF + i] = make_float4(ay*bz - az*by, az*bx - ax*bz, ax*by - ay*bx, 0.f);
        }
        {
            float ax=x1-x0, ay=y1-y0, az=z1-z0, bx=x2-x0, by=y2-y0, bz=z2-z0;
            fng[2*BNF + i] = make_float4(ay*bz - az*by, az*bx - ax*bz, ax*by - ay*bx, 0.f);
        }
    }
    {
        const float* tb = tverts + (size_t)b * V * 3;
        // replicate reference rounding: z += 10 BEFORE edges
        float x0 = tb[j0*3], y0 = tb[j0*3+1], z0 = tb[j0*3+2] + 10.0f;
        float x1 = tb[j1*3], y1 = tb[j1*3+1], z1 = tb[j1*3+2] + 10.0f;
        float x2 = tb[j2*3], y2 = tb[j2*3+1], z2 = tb[j2*3+2] + 10.0f;
        {
            float ax=x2-x1, ay=y2-y1, az=z2-z1, bx=x0-x1, by=y0-y1, bz=z0-z1;
            fnt[0*BNF + i] = make_float4(ay*bz - az*by, az*bx - ax*bz, ax*by - ay*bx, 0.f);
        }
        {
            float ax=x0-x2, ay=y0-y2, az=z0-z2, bx=x1-x2, by=y1-y2, bz=z1-z2;
            fnt[1*BNF + i] = make_float4(ay*bz - az*by, az*bx - ax*bz, ax*by - ay*bx, 0.f);
        }
        {
            float ax=x1-x0, ay=y1-y0, az=z1-z0, bx=x2-x0, by=y2-y0, bz=z2-z0;
            fnt[2*BNF + i] = make_float4(ay*bz - az*by, az*bx - ax*bz, ax*by - ay*bx, 0.f);
        }
    }
    // uv lanes 0-5
    const float* uv = fuv + (size_t)f * 9;
    float* row = ftab + (size_t)i * 16;
    *(float4*)(row + 0) = make_float4(uv[0], uv[1], uv[3], uv[4]);
    *(float2*)(row + 4) = make_float2(uv[6], uv[7]);
}

// bucket fill (needs zeroed cnt from bigfill)
__global__ void fill_k(const int* __restrict__ faces, int* __restrict__ cnt,
                       int* __restrict__ keys) {
    int f = blockIdx.x * blockDim.x + threadIdx.x;
    if (f >= NF) return;
    int j0 = faces[f*3+0], j1 = faces[f*3+1], j2 = faces[f*3+2];
    int p;
    p = atomicAdd(&cnt[j1], 1); if (p < CAP) keys[j1*CAP + p] = 0*NF + f;
    p = atomicAdd(&cnt[j2], 1); if (p < CAP) keys[j2*CAP + p] = 1*NF + f;
    p = atomicAdd(&cnt[j0], 1); if (p < CAP) keys[j0*CAP + p] = 2*NF + f;
}

// ---------------------------------------------------------------------------
// vsum: 2*B*V threads; keys in registers; unrolled min-scan selection gives
// exact reference (phase-major, face-ascending) accumulation order. Then
// scatter results straight into ftab (geo: 2B half stores; transformed: 4B).
// ---------------------------------------------------------------------------
__global__ __launch_bounds__(256) void vsum_k(
    const int*    __restrict__ cnt,
    const int*    __restrict__ keys,
    const float4* __restrict__ fng,
    const float4* __restrict__ fnt,
    float*        __restrict__ normV,
    float*        __restrict__ ftab) {
    int id = blockIdx.x * 256 + threadIdx.x;
    if (id >= 2 * BV) return;
    int half = (id >= BV) ? 1 : 0;
    int i = id - half * BV;
    int b = i / V, v = i - b * V;

    int n = min(cnt[v], CAP);
    int ks[CAP];
    const int4* kp = (const int4*)(keys + (size_t)v * CAP);
#pragma unroll
    for (int j = 0; j < CAP/4; ++j) {
        int4 t = kp[j];
        ks[4*j+0] = t.x; ks[4*j+1] = t.y; ks[4*j+2] = t.z; ks[4*j+3] = t.w;
    }
#pragma unroll
    for (int j = 0; j < CAP; ++j) ks[j] = (j < n) ? ks[j] : 0x7fffffff;

    const float4* src = half ? fnt : fng;
    float sx = 0.f, sy = 0.f, sz = 0.f;
    int last = -1;
    for (int e = 0; e < n; ++e) {
        int cur = 0x7fffffff;
#pragma unroll
        for (int j = 0; j < CAP; ++j) {
            int k = ks[j];
            bool g = (k > last) && (k < cur);
            cur = g ? k : cur;
        }
        last = cur;
        int phase = (cur >= 2*NF) ? 2 : (cur >= NF ? 1 : 0);
        int f = cur - phase * NF;
        float4 t = src[phase * BNF + b * NF + f];
        sx += t.x; sy += t.y; sz += t.z;
    }
    float inv = 1.0f / fmaxf(sqrtf(sx*sx + sy*sy + sz*sz), 1e-6f);
    if (half == 0) {
        sx *= inv; sy *= inv; sz *= inv;
        normV[i*3+0] = sx; normV[i*3+1] = sy; normV[i*3+2] = sz;
        __half hx = __float2half(sx), hy = __float2half(sy), hz = __float2half(sz);
#pragma unroll
        for (int j = 0; j < CAP; ++j) {
            if (j < n) {
                int k = ks[j];
                int phase = (k >= 2*NF) ? 2 : (k >= NF ? 1 : 0);
                int f = k - phase * NF;
                int corner = (phase == 0) ? 1 : (phase == 1 ? 2 : 0);
                __half* hp = (__half*)(ftab + ((size_t)b*NF + f) * 16);
                hp[18 + 3*corner + 0] = hx;
                hp[18 + 3*corner + 1] = hy;
                hp[18 + 3*corner + 2] = hz;
            }
        }
    } else {
        float tnz = sz * inv;
#pragma unroll
        for (int j = 0; j < CAP; ++j) {
            if (j < n) {
                int k = ks[j];
                int phase = (k >= 2*NF) ? 2 : (k >= NF ? 1 : 0);
                int f = k - phase * NF;
                int corner = (phase == 0) ? 1 : (phase == 1 ? 2 : 0);
                ftab[((size_t)b*NF + f) * 16 + 6 + corner] = tnz;
            }
        }
    }
}

// ---------------------------------------------------------------------------
// pixel: 4 adjacent pixels per thread, XCD-swizzled blocks; NT output stores.
// ---------------------------------------------------------------------------
struct PixR { float u, v, s0, s1, s2, a0, a1, a2, vis, tz; };

__device__ inline PixR shade_px(int f, float b0, float b1, float b2, int b,
                                const float* __restrict__ ftab,
                                const unsigned* __restrict__ apack,
                                const float* __restrict__ L) {
    PixR r;
    r.vis = (f >= 0) ? 1.0f : 0.0f;
    int fs = (f >= 0) ? f : 0;
    float w0 = b0 * r.vis, w1 = b1 * r.vis, w2 = b2 * r.vis;
    const float4* fr = (const float4*)(ftab + (size_t)fs * 16);
    float4 qa = fr[0];                         // u0,v0,u1,v1
    float4 qb = fr[1];                         // u2,v2,tz0,tz1
    float4 qc = fr[2];                         // tz2, p0, p1, p2
    float2 qd = *(const float2*)(ftab + (size_t)fs * 16 + 12); // p3, p4
    r.u  = w0*qa.x + w1*qa.z + w2*qb.x;
    r.v  = w0*qa.y + w1*qa.w + w2*qb.y;
    r.tz = w0*qb.z + w1*qb.w + w2*qc.x;
    float2 p0 = unpack_h2(qc.y);   // n0x,n0y
    float2 p1 = unpack_h2(qc.z);   // n0z,n1x
    float2 p2 = unpack_h2(qc.w);   // n1y,n1z
    float2 p3 = unpack_h2(qd.x);   // n2x,n2y
    float2 p4 = unpack_h2(qd.y);   // n2z,-
    float nx = w0*p0.x + w1*p1.y + w2*p3.x;
    float ny = w0*p0.y + w1*p2.x + w2*p3.y;
    float nz = w0*p1.x + w1*p2.y + w2*p4.x;

    float shb[9] = {C0, C1*nx, C1*ny, C1*nz, C4*nx*ny, C4*nx*nz, C4*ny*nz,
                    C7*(nx*nx - ny*ny), C8*(3.0f*nz*nz - 1.0f)};
    float s0 = 0.0f, s1 = 0.0f, s2 = 0.0f;
#pragma unroll
    for (int k = 0; k < 9; ++k) {
        float sk = shb[k];
        s0 += L[k*3+0]*sk; s1 += L[k*3+1]*sk; s2 += L[k*3+2]*sk;
    }
    r.s0 = s0; r.s1 = s1; r.s2 = s2;

    float gx = (r.u + 1.0f) * 0.5f * (float)W - 0.5f;
    float gy = (r.v + 1.0f) * 0.5f * (float)H - 0.5f;
    float x0 = floorf(gx), y0 = floorf(gy);
    float wx1 = gx - x0, wx0 = 1.0f - wx1;
    float wy1 = gy - y0, wy0 = 1.0f - wy1;
    float a0 = 0.0f, a1 = 0.0f, a2 = 0.0f;
    float fx[4] = {x0, x0 + 1.0f, x0,        x0 + 1.0f};
    float fy[4] = {y0, y0,        y0 + 1.0f, y0 + 1.0f};
    float wt[4] = {wx0*wy0, wx1*wy0, wx0*wy1, wx1*wy1};
#pragma unroll
    for (int c = 0; c < 4; ++c) {
        bool valid = (fx[c] >= 0.0f) && (fx[c] <= (float)(W-1)) &&
                     (fy[c] >= 0.0f) && (fy[c] <= (float)(H-1));
        if (valid) {
            int ix = (int)fx[c];
            int iy = (int)fy[c];
            float3 t = dequant_rgb(apack[(b << 18) + iy * W + ix]);
            float wgt = wt[c];
            a0 += wgt * t.x; a1 += wgt * t.y; a2 += wgt * t.z;
        }
    }
    r.a0 = a0; r.a1 = a1; r.a2 = a2;
    return r;
}

__global__ __launch_bounds__(256) void pixel_k(
    const int*    __restrict__ ptf,
    const float*  __restrict__ bary,
    const unsigned* __restrict__ apack,
    const float*  __restrict__ lights,
    const float*  __restrict__ ftab,
    float*        __restrict__ out) {
    // 1024 blocks; XCD swizzle -> contiguous 128-block chunk per XCD
    int bid = blockIdx.x;
    int dataBid = (bid & 7) * (NPIX / 1024 / 8) + (bid >> 3);
    int pix = dataBid * 1024 + threadIdx.x * 4;    // 4 adjacent px, same batch
    int b  = pix >> 18;
    int hw = pix & (HW - 1);

    int4 ff = *(const int4*)(ptf + pix);
    const float4* b4 = (const float4*)(bary + (size_t)pix * 3);
    float4 c0 = b4[0], c1 = b4[1], c2 = b4[2];
    const float* L = lights + (size_t)__builtin_amdgcn_readfirstlane(b) * 27;

    PixR P0 = shade_px(ff.x, c0.x, c0.y, c0.z, b, ftab, apack, L);
    PixR P1 = shade_px(ff.y, c0.w, c1.x, c1.y, b, ftab, apack, L);
    PixR P2 = shade_px(ff.z, c1.z, c1.w, c2.x, b, ftab, apack, L);
    PixR P3 = shade_px(ff.w, c2.y, c2.z, c2.w, b, ftab, apack, L);

    int obase = b * 3 * HW + hw;
    nt_store4(out + OFF_IMAGES + obase        , make_float4(
        P0.a0*P0.s0*P0.vis, P1.a0*P1.s0*P1.vis, P2.a0*P2.s0*P2.vis, P3.a0*P3.s0*P3.vis));
    nt_store4(out + OFF_IMAGES + obase +  HW  , make_float4(
        P0.a1*P0.s1*P0.vis, P1.a1*P1.s1*P1.vis, P2.a1*P2.s1*P2.vis, P3.a1*P3.s1*P3.vis));
    nt_store4(out + OFF_IMAGES + obase + 2*HW , make_float4(
        P0.a2*P0.s2*P0.vis, P1.a2*P1.s2*P1.vis, P2.a2*P2.s2*P2.vis, P3.a2*P3.s2*P3.vis));
    nt_store4(out + OFF_ALBEDO + obase        , make_float4(P0.a0, P1.a0, P2.a0, P3.a0));
    nt_store4(out + OFF_ALBEDO + obase +  HW  , make_float4(P0.a1, P1.a1, P2.a1, P3.a1));
    nt_store4(out + OFF_ALBEDO + obase + 2*HW , make_float4(P0.a2, P1.a2, P2.a2, P3.a2));
    nt_store4(out + OFF_ALPHA   + pix, make_float4(P0.vis, P1.vis, P2.vis, P3.vis));
    nt_store4(out + OFF_POSMASK + pix, make_float4(
        P0.tz < -0.05f ? 1.0f : 0.0f, P1.tz < -0.05f ? 1.0f : 0.0f,
        P2.tz < -0.05f ? 1.0f : 0.0f, P3.tz < -0.05f ? 1.0f : 0.0f));
    nt_store4(out + OFF_SHADING + obase       , make_float4(P0.s0, P1.s0, P2.s0, P3.s0));
    nt_store4(out + OFF_SHADING + obase +  HW , make_float4(P0.s1, P1.s1, P2.s1, P3.s1));
    nt_store4(out + OFF_SHADING + obase + 2*HW, make_float4(P0.s2, P1.s2, P2.s2, P3.s2));
    nt_store4(out + OFF_GRID + (size_t)pix*2    , make_float4(P0.u, P0.v, P1.u, P1.v));
    nt_store4(out + OFF_GRID + (size_t)pix*2 + 4, make_float4(P2.u, P2.v, P3.u, P3.v));
}

} // namespace

extern "C" void kernel_launch(void* const* d_in, const int* in_sizes, int n_in,
                              void* d_out, int out_size, void* d_ws, size_t ws_size,
                              hipStream_t stream) {
    const float* verts  = (const float*)d_in[0];
    const float* tverts = (const float*)d_in[1];
    const float* albedo = (const float*)d_in[2];
    const float* lights = (const float*)d_in[3];
    const float* fuv    = (const float*)d_in[4];
    const float* bary   = (const float*)d_in[5];
    const int*   faces  = (const int*)d_in[6];
    const int*   ptf    = (const int*)d_in[7];
    float* out = (float*)d_out;

    char* ws = (char*)d_ws;
    int*    cnt   = (int*)ws;                               // V
    int*    keys  = cnt + V;                                // V*CAP
    char*   pend  = (char*)(keys + (size_t)V*CAP);
    size_t base      = (size_t)(pend - ws);
    size_t fng_off   = (base + 255) & ~(size_t)255;
    size_t fnt_off   = (fng_off + (size_t)3*BNF*sizeof(float4) + 255) & ~(size_t)255;
    size_t ftab_off  = (fnt_off + (size_t)3*BNF*sizeof(float4) + 255) & ~(size_t)255;
    size_t apack_off = (ftab_off + (size_t)BNF*16*sizeof(float) + 255) & ~(size_t)255;
    float4*   fng   = (float4*)(ws + fng_off);              // 1.92 MB
    float4*   fnt   = (float4*)(ws + fnt_off);              // 1.92 MB
    float*    ftab  = (float*)(ws + ftab_off);              // 2.56 MB (64B rows)
    unsigned* apack = (unsigned*)(ws + apack_off);          // 4.19 MB
    float* normV = out + OFF_NORMALS;

    bigfill_k<<<(NPIX + BNF + 255)/256, 256, 0, stream>>>(faces, fuv, verts, tverts,
                                                          albedo, cnt, fng, fnt,
                                                          ftab, apack);
    fill_k<<<(NF + 255)/256, 256, 0, stream>>>(faces, cnt, keys);
    vsum_k<<<(2*BV + 255)/256, 256, 0, stream>>>(cnt, keys, fng, fnt, normV, ftab);
    pixel_k<<<NPIX/1024, 256, 0, stream>>>(ptf, bary, apack, lights, ftab, out);
}

// Round 19
// 69.259 us; speedup vs baseline: 1.1124x; 1.0877x over previous
//
#include <hip/hip_runtime.h>
#include <hip/hip_fp16.h>

namespace {

constexpr int B  = 4;
constexpr int V  = 5000;
constexpr int NF = 10000;
constexpr int H  = 512;
constexpr int W  = 512;
constexpr int HW = H * W;          // 2^18
constexpr int NPIX = B * HW;
constexpr int CAP = 32;            // max vertex degree bucket (validated r12-18)
constexpr int BNF = B * NF;
constexpr int BV  = B * V;
constexpr int NQ  = NPIX / 4;      // repack quads

// output float offsets
constexpr int OFF_IMAGES  = 0;
constexpr int OFF_ALBEDO  = 3 * NPIX;
constexpr int OFF_ALPHA   = OFF_ALBEDO + 3 * NPIX;
constexpr int OFF_POSMASK = OFF_ALPHA + NPIX;
constexpr int OFF_SHADING = OFF_POSMASK + NPIX;
constexpr int OFF_GRID    = OFF_SHADING + 3 * NPIX;
constexpr int OFF_NORMALS = OFF_GRID + 2 * NPIX;

// SH constants
constexpr float C0 = 0.28209479177387814f;
constexpr float C1 = 1.0233267079464885f;
constexpr float C4 = 0.8580855308097834f;
constexpr float C7 = 0.42904276540489156f;
constexpr float C8 = 0.24770795610037571f;

__device__ inline float2 unpack_h2(float fbits) {
    __half2 h = *reinterpret_cast<__half2*>(&fbits);
    return __half22float2(h);
}
// albedo 11/11/10 fixed-point pack (values in [0,1)); err <= 4.9e-4
__device__ inline unsigned quant_rgb(float r, float g, float bch) {
    unsigned qr = (unsigned)fmaf(r,   2047.0f, 0.5f);
    unsigned qg = (unsigned)fmaf(g,   2047.0f, 0.5f);
    unsigned qb = (unsigned)fmaf(bch, 1023.0f, 0.5f);
    return qr | (qg << 11) | (qb << 22);
}
__device__ inline float3 dequant_rgb(unsigned w) {
    return make_float3((float)(w & 2047u)         * (1.0f/2047.0f),
                       (float)((w >> 11) & 2047u) * (1.0f/2047.0f),
                       (float)(w >> 22)           * (1.0f/1023.0f));
}

// ---------------------------------------------------------------------------
// ftab row: 16 float lanes (64B, one aligned line):
//  0:u0 1:v0 2:u1 3:v1 4:u2 5:v2 6:tz0 7:tz1 8:tz2
//  9..13: 9 fp16 normals as half-lanes h[18..26] = n0x n0y n0z n1x n1y n1z n2x n2y n2z
// bigfill writes lanes 0-5; vsum scatters lanes 6-8 (fp32) + halves 18-26.
// key = phase*NF + f ; phase 0 = slot1, 1 = slot2, 2 = slot0 (reference order)
// ---------------------------------------------------------------------------
__global__ __launch_bounds__(256) void bigfill_k(
    const int*   __restrict__ faces,
    const float* __restrict__ fuv,
    const float* __restrict__ verts,
    const float* __restrict__ tverts,
    const float* __restrict__ albedo,
    int*         __restrict__ cnt,
    float4*      __restrict__ fng,
    float4*      __restrict__ fnt,
    float*       __restrict__ ftab,
    uint4*       __restrict__ apack4) {
    int gid = blockIdx.x * 256 + threadIdx.x;
    if (gid < V) cnt[gid] = 0;     // cnt consumed only by fill_k (next node)
    if (gid < NQ) {
        // 4 texels per thread: vectorized plane loads + one uint4 store
        int idx = gid * 4;
        int b = idx >> 18, hw = idx & (HW - 1);
        const float* ab = albedo + (size_t)b * 3 * HW;
        float4 r4 = *(const float4*)(ab + hw);
        float4 g4 = *(const float4*)(ab + HW + hw);
        float4 u4 = *(const float4*)(ab + 2*HW + hw);
        uint4 q;
        q.x = quant_rgb(r4.x, g4.x, u4.x);
        q.y = quant_rgb(r4.y, g4.y, u4.y);
        q.z = quant_rgb(r4.z, g4.z, u4.z);
        q.w = quant_rgb(r4.w, g4.w, u4.w);
        apack4[gid] = q;
        return;
    }
    int i = gid - NQ;
    if (i >= BNF) return;
    int b = i / NF, f = i - b * NF;
    int j0 = faces[f*3+0], j1 = faces[f*3+1], j2 = faces[f*3+2];

    {
        const float* vb = verts + (size_t)b * V * 3;
        float x0 = vb[j0*3], y0 = vb[j0*3+1], z0 = vb[j0*3+2];
        float x1 = vb[j1*3], y1 = vb[j1*3+1], z1 = vb[j1*3+2];
        float x2 = vb[j2*3], y2 = vb[j2*3+1], z2 = vb[j2*3+2];
        {
            float ax=x2-x1, ay=y2-y1, az=z2-z1, bx=x0-x1, by=y0-y1, bz=z0-z1;
            fng[0*BNF + i] = make_float4(ay*bz - az*by, az*bx - ax*bz, ax*by - ay*bx, 0.f);
        }
        {
            float ax=x0-x2, ay=y0-y2, az=z0-z2, bx=x1-x2, by=y1-y2, bz=z1-z2;
            fng[1*BNF + i] = make_float4(ay*bz - az*by, az*bx - ax*bz, ax*by - ay*bx, 0.f);
        }
        {
            float ax=x1-x0, ay=y1-y0, az=z1-z0, bx=x2-x0, by=y2-y0, bz=z2-z0;
            fng[2*BNF + i] = make_float4(ay*bz - az*by, az*bx - ax*bz, ax*by - ay*bx, 0.f);
        }
    }
    {
        const float* tb = tverts + (size_t)b * V * 3;
        // replicate reference rounding: z += 10 BEFORE edges
        float x0 = tb[j0*3], y0 = tb[j0*3+1], z0 = tb[j0*3+2] + 10.0f;
        float x1 = tb[j1*3], y1 = tb[j1*3+1], z1 = tb[j1*3+2] + 10.0f;
        float x2 = tb[j2*3], y2 = tb[j2*3+1], z2 = tb[j2*3+2] + 10.0f;
        {
            float ax=x2-x1, ay=y2-y1, az=z2-z1, bx=x0-x1, by=y0-y1, bz=z0-z1;
            fnt[0*BNF + i] = make_float4(ay*bz - az*by, az*bx - ax*bz, ax*by - ay*bx, 0.f);
        }
        {
            float ax=x0-x2, ay=y0-y2, az=z0-z2, bx=x1-x2, by=y1-y2, bz=z1-z2;
            fnt[1*BNF + i] = make_float4(ay*bz - az*by, az*bx - ax*bz, ax*by - ay*bx, 0.f);
        }
        {
            float ax=x1-x0, ay=y1-y0, az=z1-z0, bx=x2-x0, by=y2-y0, bz=z2-z0;
            fnt[2*BNF + i] = make_float4(ay*bz - az*by, az*bx - ax*bz, ax*by - ay*bx, 0.f);
        }
    }
    // uv lanes 0-5
    const float* uv = fuv + (size_t)f * 9;
    float* row = ftab + (size_t)i * 16;
    *(float4*)(row + 0) = make_float4(uv[0], uv[1], uv[3], uv[4]);
    *(float2*)(row + 4) = make_float2(uv[6], uv[7]);
}

// bucket fill (needs zeroed cnt from bigfill)
__global__ void fill_k(const int* __restrict__ faces, int* __restrict__ cnt,
                       int* __restrict__ keys) {
    int f = blockIdx.x * blockDim.x + threadIdx.x;
    if (f >= NF) return;
    int j0 = faces[f*3+0], j1 = faces[f*3+1], j2 = faces[f*3+2];
    int p;
    p = atomicAdd(&cnt[j1], 1); if (p < CAP) keys[j1*CAP + p] = 0*NF + f;
    p = atomicAdd(&cnt[j2], 1); if (p < CAP) keys[j2*CAP + p] = 1*NF + f;
    p = atomicAdd(&cnt[j0], 1); if (p < CAP) keys[j0*CAP + p] = 2*NF + f;
}

// ---------------------------------------------------------------------------
// vsum: 2*B*V threads; keys in registers; unrolled min-scan selection gives
// exact reference (phase-major, face-ascending) accumulation order. Then
// scatter results straight into ftab (geo: 2B half stores; transformed: 4B).
// ---------------------------------------------------------------------------
__global__ __launch_bounds__(256) void vsum_k(
    const int*    __restrict__ cnt,
    const int*    __restrict__ keys,
    const float4* __restrict__ fng,
    const float4* __restrict__ fnt,
    float*        __restrict__ normV,
    float*        __restrict__ ftab) {
    int id = blockIdx.x * 256 + threadIdx.x;
    if (id >= 2 * BV) return;
    int half = (id >= BV) ? 1 : 0;
    int i = id - half * BV;
    int b = i / V, v = i - b * V;

    int n = min(cnt[v], CAP);
    int ks[CAP];
    const int4* kp = (const int4*)(keys + (size_t)v * CAP);
#pragma unroll
    for (int j = 0; j < CAP/4; ++j) {
        int4 t = kp[j];
        ks[4*j+0] = t.x; ks[4*j+1] = t.y; ks[4*j+2] = t.z; ks[4*j+3] = t.w;
    }
#pragma unroll
    for (int j = 0; j < CAP; ++j) ks[j] = (j < n) ? ks[j] : 0x7fffffff;

    const float4* src = half ? fnt : fng;
    float sx = 0.f, sy = 0.f, sz = 0.f;
    int last = -1;
    for (int e = 0; e < n; ++e) {
        int cur = 0x7fffffff;
#pragma unroll
        for (int j = 0; j < CAP; ++j) {
            int k = ks[j];
            bool g = (k > last) && (k < cur);
            cur = g ? k : cur;
        }
        last = cur;
        int phase = (cur >= 2*NF) ? 2 : (cur >= NF ? 1 : 0);
        int f = cur - phase * NF;
        float4 t = src[phase * BNF + b * NF + f];
        sx += t.x; sy += t.y; sz += t.z;
    }
    float inv = 1.0f / fmaxf(sqrtf(sx*sx + sy*sy + sz*sz), 1e-6f);
    if (half == 0) {
        sx *= inv; sy *= inv; sz *= inv;
        normV[i*3+0] = sx; normV[i*3+1] = sy; normV[i*3+2] = sz;
        __half hx = __float2half(sx), hy = __float2half(sy), hz = __float2half(sz);
#pragma unroll
        for (int j = 0; j < CAP; ++j) {
            if (j < n) {
                int k = ks[j];
                int phase = (k >= 2*NF) ? 2 : (k >= NF ? 1 : 0);
                int f = k - phase * NF;
                int corner = (phase == 0) ? 1 : (phase == 1 ? 2 : 0);
                __half* hp = (__half*)(ftab + ((size_t)b*NF + f) * 16);
                hp[18 + 3*corner + 0] = hx;
                hp[18 + 3*corner + 1] = hy;
                hp[18 + 3*corner + 2] = hz;
            }
        }
    } else {
        float tnz = sz * inv;
#pragma unroll
        for (int j = 0; j < CAP; ++j) {
            if (j < n) {
                int k = ks[j];
                int phase = (k >= 2*NF) ? 2 : (k >= NF ? 1 : 0);
                int f = k - phase * NF;
                int corner = (phase == 0) ? 1 : (phase == 1 ? 2 : 0);
                ftab[((size_t)b*NF + f) * 16 + 6 + corner] = tnz;
            }
        }
    }
}

// ---------------------------------------------------------------------------
// pixel: 4 adjacent pixels per thread, XCD-swizzled blocks.
// ---------------------------------------------------------------------------
struct PixR { float u, v, s0, s1, s2, a0, a1, a2, vis, tz; };

__device__ inline PixR shade_px(int f, float b0, float b1, float b2, int b,
                                const float* __restrict__ ftab,
                                const unsigned* __restrict__ apack,
                                const float* __restrict__ L) {
    PixR r;
    r.vis = (f >= 0) ? 1.0f : 0.0f;
    int fs = (f >= 0) ? f : 0;
    float w0 = b0 * r.vis, w1 = b1 * r.vis, w2 = b2 * r.vis;
    const float4* fr = (const float4*)(ftab + (size_t)fs * 16);
    float4 qa = fr[0];                         // u0,v0,u1,v1
    float4 qb = fr[1];                         // u2,v2,tz0,tz1
    float4 qc = fr[2];                         // tz2, p0, p1, p2
    float2 qd = *(const float2*)(ftab + (size_t)fs * 16 + 12); // p3, p4
    r.u  = w0*qa.x + w1*qa.z + w2*qb.x;
    r.v  = w0*qa.y + w1*qa.w + w2*qb.y;
    r.tz = w0*qb.z + w1*qb.w + w2*qc.x;
    float2 p0 = unpack_h2(qc.y);   // n0x,n0y
    float2 p1 = unpack_h2(qc.z);   // n0z,n1x
    float2 p2 = unpack_h2(qc.w);   // n1y,n1z
    float2 p3 = unpack_h2(qd.x);   // n2x,n2y
    float2 p4 = unpack_h2(qd.y);   // n2z,-
    float nx = w0*p0.x + w1*p1.y + w2*p3.x;
    float ny = w0*p0.y + w1*p2.x + w2*p3.y;
    float nz = w0*p1.x + w1*p2.y + w2*p4.x;

    float shb[9] = {C0, C1*nx, C1*ny, C1*nz, C4*nx*ny, C4*nx*nz, C4*ny*nz,
                    C7*(nx*nx - ny*ny), C8*(3.0f*nz*nz - 1.0f)};
    float s0 = 0.0f, s1 = 0.0f, s2 = 0.0f;
#pragma unroll
    for (int k = 0; k < 9; ++k) {
        float sk = shb[k];
        s0 += L[k*3+0]*sk; s1 += L[k*3+1]*sk; s2 += L[k*3+2]*sk;
    }
    r.s0 = s0; r.s1 = s1; r.s2 = s2;

    float gx = (r.u + 1.0f) * 0.5f * (float)W - 0.5f;
    float gy = (r.v + 1.0f) * 0.5f * (float)H - 0.5f;
    float x0 = floorf(gx), y0 = floorf(gy);
    float wx1 = gx - x0, wx0 = 1.0f - wx1;
    float wy1 = gy - y0, wy0 = 1.0f - wy1;
    float a0 = 0.0f, a1 = 0.0f, a2 = 0.0f;
    float fx[4] = {x0, x0 + 1.0f, x0,        x0 + 1.0f};
    float fy[4] = {y0, y0,        y0 + 1.0f, y0 + 1.0f};
    float wt[4] = {wx0*wy0, wx1*wy0, wx0*wy1, wx1*wy1};
#pragma unroll
    for (int c = 0; c < 4; ++c) {
        bool valid = (fx[c] >= 0.0f) && (fx[c] <= (float)(W-1)) &&
                     (fy[c] >= 0.0f) && (fy[c] <= (float)(H-1));
        if (valid) {
            int ix = (int)fx[c];
            int iy = (int)fy[c];
            float3 t = dequant_rgb(apack[(b << 18) + iy * W + ix]);
            float wgt = wt[c];
            a0 += wgt * t.x; a1 += wgt * t.y; a2 += wgt * t.z;
        }
    }
    r.a0 = a0; r.a1 = a1; r.a2 = a2;
    return r;
}

__global__ __launch_bounds__(256) void pixel_k(
    const int*    __restrict__ ptf,
    const float*  __restrict__ bary,
    const unsigned* __restrict__ apack,
    const float*  __restrict__ lights,
    const float*  __restrict__ ftab,
    float*        __restrict__ out) {
    // 1024 blocks; XCD swizzle -> contiguous 128-block chunk per XCD
    int bid = blockIdx.x;
    int dataBid = (bid & 7) * (NPIX / 1024 / 8) + (bid >> 3);
    int pix = dataBid * 1024 + threadIdx.x * 4;    // 4 adjacent px, same batch
    int b  = pix >> 18;
    int hw = pix & (HW - 1);

    int4 ff = *(const int4*)(ptf + pix);
    const float4* b4 = (const float4*)(bary + (size_t)pix * 3);
    float4 c0 = b4[0], c1 = b4[1], c2 = b4[2];
    const float* L = lights + (size_t)__builtin_amdgcn_readfirstlane(b) * 27;

    PixR P0 = shade_px(ff.x, c0.x, c0.y, c0.z, b, ftab, apack, L);
    PixR P1 = shade_px(ff.y, c0.w, c1.x, c1.y, b, ftab, apack, L);
    PixR P2 = shade_px(ff.z, c1.z, c1.w, c2.x, b, ftab, apack, L);
    PixR P3 = shade_px(ff.w, c2.y, c2.z, c2.w, b, ftab, apack, L);

    int obase = b * 3 * HW + hw;
    *(float4*)(out + OFF_IMAGES + obase       ) = make_float4(
        P0.a0*P0.s0*P0.vis, P1.a0*P1.s0*P1.vis, P2.a0*P2.s0*P2.vis, P3.a0*P3.s0*P3.vis);
    *(float4*)(out + OFF_IMAGES + obase +  HW ) = make_float4(
        P0.a1*P0.s1*P0.vis, P1.a1*P1.s1*P1.vis, P2.a1*P2.s1*P2.vis, P3.a1*P3.s1*P3.vis);
    *(float4*)(out + OFF_IMAGES + obase + 2*HW) = make_float4(
        P0.a2*P0.s2*P0.vis, P1.a2*P1.s2*P1.vis, P2.a2*P2.s2*P2.vis, P3.a2*P3.s2*P3.vis);
    *(float4*)(out + OFF_ALBEDO + obase       ) = make_float4(P0.a0, P1.a0, P2.a0, P3.a0);
    *(float4*)(out + OFF_ALBEDO + obase +  HW ) = make_float4(P0.a1, P1.a1, P2.a1, P3.a1);
    *(float4*)(out + OFF_ALBEDO + obase + 2*HW) = make_float4(P0.a2, P1.a2, P2.a2, P3.a2);
    *(float4*)(out + OFF_ALPHA   + pix) = make_float4(P0.vis, P1.vis, P2.vis, P3.vis);
    *(float4*)(out + OFF_POSMASK + pix) = make_float4(
        P0.tz < -0.05f ? 1.0f : 0.0f, P1.tz < -0.05f ? 1.0f : 0.0f,
        P2.tz < -0.05f ? 1.0f : 0.0f, P3.tz < -0.05f ? 1.0f : 0.0f);
    *(float4*)(out + OFF_SHADING + obase       ) = make_float4(P0.s0, P1.s0, P2.s0, P3.s0);
    *(float4*)(out + OFF_SHADING + obase +  HW ) = make_float4(P0.s1, P1.s1, P2.s1, P3.s1);
    *(float4*)(out + OFF_SHADING + obase + 2*HW) = make_float4(P0.s2, P1.s2, P2.s2, P3.s2);
    *(float4*)(out + OFF_GRID + (size_t)pix*2    ) = make_float4(P0.u, P0.v, P1.u, P1.v);
    *(float4*)(out + OFF_GRID + (size_t)pix*2 + 4) = make_float4(P2.u, P2.v, P3.u, P3.v);
}

} // namespace

extern "C" void kernel_launch(void* const* d_in, const int* in_sizes, int n_in,
                              void* d_out, int out_size, void* d_ws, size_t ws_size,
                              hipStream_t stream) {
    const float* verts  = (const float*)d_in[0];
    const float* tverts = (const float*)d_in[1];
    const float* albedo = (const float*)d_in[2];
    const float* lights = (const float*)d_in[3];
    const float* fuv    = (const float*)d_in[4];
    const float* bary   = (const float*)d_in[5];
    const int*   faces  = (const int*)d_in[6];
    const int*   ptf    = (const int*)d_in[7];
    float* out = (float*)d_out;

    char* ws = (char*)d_ws;
    int*    cnt   = (int*)ws;                               // V
    int*    keys  = cnt + V;                                // V*CAP
    char*   pend  = (char*)(keys + (size_t)V*CAP);
    size_t base      = (size_t)(pend - ws);
    size_t fng_off   = (base + 255) & ~(size_t)255;
    size_t fnt_off   = (fng_off + (size_t)3*BNF*sizeof(float4) + 255) & ~(size_t)255;
    size_t ftab_off  = (fnt_off + (size_t)3*BNF*sizeof(float4) + 255) & ~(size_t)255;
    size_t apack_off = (ftab_off + (size_t)BNF*16*sizeof(float) + 255) & ~(size_t)255;
    float4*   fng   = (float4*)(ws + fng_off);              // 1.92 MB
    float4*   fnt   = (float4*)(ws + fnt_off);              // 1.92 MB
    float*    ftab  = (float*)(ws + ftab_off);              // 2.56 MB (64B rows)
    unsigned* apack = (unsigned*)(ws + apack_off);          // 4.19 MB
    float* normV = out + OFF_NORMALS;

    bigfill_k<<<(NQ + BNF + 255)/256, 256, 0, stream>>>(faces, fuv, verts, tverts,
                                                        albedo, cnt, fng, fnt,
                                                        ftab, (uint4*)apack);
    fill_k<<<(NF + 255)/256, 256, 0, stream>>>(faces, cnt, keys);
    vsum_k<<<(2*BV + 255)/256, 256, 0, stream>>>(cnt, keys, fng, fnt, normV, ftab);
    pixel_k<<<NPIX/1024, 256, 0, stream>>>(ptf, bary, apack, lights, ftab, out);
}